// Round 7
// baseline (219.265 us; speedup 1.0000x reference)
//
#include <hip/hip_runtime.h>
#include <hip/hip_cooperative_groups.h>
#include <hip/hip_bf16.h>
#include <stdint.h>

namespace cg = cooperative_groups;

typedef __attribute__((ext_vector_type(8))) __bf16 bf16x8;
typedef __attribute__((ext_vector_type(4))) float f32x4;

#define N_PTS 1600
#define HD    64

// ---- ws layout (bytes); total 4.49 MB ----
#define OFF_XC   0u          //  819200 : [1600][256] bf16 canonical x
#define OFF_WT   819200u     //  393216 : 3 x [256 o][256 k] bf16 transposed W
#define OFF_BIAS 1212416u    //    1536 : 3 x 256 bf16
#define OFF_VHT  1213952u    //  819200 : [4][64][1600] raw V^T
#define OFF_QH   2033152u    //  819200 : [4][1600][64] bf16 Q (pre-scaled 1/16)
#define OFF_KH   2852352u    //  819200 : [4][1600][64] bf16 K
#define OFF_VST  3671552u    //  819200 : [4][64][1600] bf16 smoothed V^T

struct SMem {
  union {
    struct { ushort obuf[256][66]; float lbuf[256]; } d;  // attn reduce (~35 KB)
    ushort tileb[32][33];                                 // W transpose
  } u;
  int shflag;
};

__device__ __forceinline__ float bf2f(ushort h) {
  union { uint32_t u; float f; } v; v.u = ((uint32_t)h) << 16; return v.f;
}
__device__ __forceinline__ ushort f2bf(float f) {
  union { float f; uint32_t u; } v; v.f = f;
  uint32_t u = v.u;
  return (ushort)((u + 0x7FFFu + ((u >> 16) & 1u)) >> 16);
}

// block-uniform dtype detect: sample x's first 4 KB; f32 buffers decode as huge/NaN bf16
__device__ __forceinline__ int detect_f32(const ushort* xu, SMem& sm, int t) {
  if (t == 0) sm.shflag = 0;
  __syncthreads();
  int tt = t & 255, local = 0;
#pragma unroll
  for (int i = 0; i < 4; ++i) {
    float v = bf2f(xu[(tt * 4 + i) * 2]);
    if (!(fabsf(v) < 1e4f)) local = 1;
  }
  if (local) atomicOr(&sm.shflag, 1);
  __syncthreads();
  return sm.shflag;
}

// ---- Phase A: canonicalize x + biases, transpose+convert W (needs >=193 blocks) ----
__device__ __forceinline__ void phaseA(const void* x, const void* Wq, const void* bq,
                                       const void* Wk, const void* bk, const void* Wv,
                                       const void* bv, char* ws, SMem& sm,
                                       int isf32, int b, int t) {
  {
    int g = b * 1024 + t;  // 204800 threads x ushort2 = 409600 elems
    ushort2 o;
    if (isf32) { float2 f = ((const float2*)x)[g]; o.x = f2bf(f.x); o.y = f2bf(f.y); }
    else o = ((const ushort2*)x)[g];
    ((ushort2*)(ws + OFF_XC))[g] = o;
  }
  if (b < 192) {  // 3 z x 64 tiles of 32x32, one tile per block
    int z = b >> 6, tile = b & 63;
    const void* W = (z == 0) ? Wq : ((z == 1) ? Wk : Wv);
    int o0 = (tile & 7) * 32, k0 = (tile >> 3) * 32;
    int tx = t & 31, ty = t >> 5;
    int kk = (k0 + ty) * 256 + o0 + tx;
    sm.u.tileb[ty][tx] = isf32 ? f2bf(((const float*)W)[kk]) : ((const ushort*)W)[kk];
    __syncthreads();
    ((ushort*)(ws + OFF_WT))[z * 65536 + (o0 + ty) * 256 + k0 + tx] = sm.u.tileb[tx][ty];
  } else if (b == 192 && t < 768) {
    int z = t >> 8, i = t & 255;
    const void* B = (z == 0) ? bq : ((z == 1) ? bk : bv);
    ((ushort*)(ws + OFF_BIAS))[t] = isf32 ? f2bf(((const float*)B)[i]) : ((const ushort*)B)[i];
  }
}

// ---- Phase B: projections (1200 MFMA waves over blocks 0..74) ----
__device__ __forceinline__ void phaseB(char* ws, int b, int t) {
  int w = (b << 4) + (t >> 6);
  if (w >= 1200) return;
  int head = w & 3;
  int unit = w >> 2;
  int z = unit / 100;
  int qt = unit - z * 100;
  int lane = t & 63, c = lane & 15, quad = lane >> 4;
  int n0 = qt * 16;
  const ushort* X = (const ushort*)(ws + OFF_XC);
  const ushort* WTz = (const ushort*)(ws + OFF_WT) + z * 65536;
  const ushort* bias = (const ushort*)(ws + OFF_BIAS) + z * 256;

  f32x4 acc[4];
#pragma unroll
  for (int i = 0; i < 4; ++i) acc[i] = (f32x4){0.f, 0.f, 0.f, 0.f};
  const ushort* xrow = X + (n0 + c) * 256;
#pragma unroll
  for (int kt = 0; kt < 8; ++kt) {
    bf16x8 a = *(const bf16x8*)(xrow + kt * 32 + quad * 8);
#pragma unroll
    for (int os = 0; os < 4; ++os) {
      bf16x8 bfr = *(const bf16x8*)(WTz + (head * 64 + os * 16 + c) * 256 + kt * 32 + quad * 8);
      acc[os] = __builtin_amdgcn_mfma_f32_16x16x32_bf16(a, bfr, acc[os], 0, 0, 0);
    }
  }
  if (z == 2) {
    ushort* VhT = (ushort*)(ws + OFF_VHT);
#pragma unroll
    for (int os = 0; os < 4; ++os) {
      float bval = bf2f(bias[head * 64 + os * 16 + c]);
      ushort4 v;
      v.x = f2bf(acc[os][0] + bval); v.y = f2bf(acc[os][1] + bval);
      v.z = f2bf(acc[os][2] + bval); v.w = f2bf(acc[os][3] + bval);
      *(ushort4*)(VhT + (head * 64 + os * 16 + c) * N_PTS + n0 + quad * 4) = v;
    }
  } else {
    float scale = (z == 0) ? 0.0625f : 1.0f;  // fold scores/sqrt(256) into Q
    ushort* o = (ushort*)(ws + ((z == 0) ? OFF_QH : OFF_KH));
#pragma unroll
    for (int os = 0; os < 4; ++os) {
      float bval = bf2f(bias[head * 64 + os * 16 + c]);
#pragma unroll
      for (int r = 0; r < 4; ++r)
        o[head * (N_PTS * HD) + (n0 + quad * 4 + r) * HD + os * 16 + c] =
            f2bf((acc[os][r] + bval) * scale);
    }
  }
}

// ---- Phase C: smooth V^T along m, shifts {-4,-2,0,2,4} circular ----
__device__ __forceinline__ void phaseC(char* ws, int b, int t) {
  const ushort* VhT = (const ushort*)(ws + OFF_VHT);
  ushort* VsT = (ushort*)(ws + OFF_VST);
  int i0 = b * 1024 + t;
#pragma unroll
  for (int rep = 0; rep < 2; ++rep) {
    int i = i0 + rep * 204800;
    int m = i % N_PTS;
    int base = i - m;
    float s = 0.f;
#pragma unroll
    for (int sh = -4; sh <= 4; sh += 2)
      s += bf2f(VhT[base + ((m + sh + N_PTS) % N_PTS)]);
    VsT[i] = f2bf(s);
  }
}

// build PV B-fragment from S^T C-layout via quad shuffles (validated R4/R5)
__device__ __forceinline__ bf16x8 build_pfrag(const f32x4& s0, const f32x4& s1,
                                              int sA, int sB, bool low, float& lpart) {
  uint32_t pk[4];
#pragma unroll
  for (int r = 0; r < 4; ++r) {
    float p0 = __expf(s0[r]);
    float p1 = __expf(s1[r]);
    lpart += p0 + p1;
    __hip_bfloat162 h2 = __float22bfloat162_rn(make_float2(p0, p1));
    union { __hip_bfloat162 h; uint32_t u; } cv; cv.h = h2;
    pk[r] = cv.u;
  }
  union { ushort us[8]; bf16x8 v; } pb;
#pragma unroll
  for (int j = 0; j < 4; ++j) {
    uint32_t u = (uint32_t)__shfl((int)pk[j], sA, 64);
    pb.us[j] = low ? (ushort)u : (ushort)(u >> 16);
  }
#pragma unroll
  for (int j = 0; j < 4; ++j) {
    uint32_t u = (uint32_t)__shfl((int)pk[j], sB, 64);
    pb.us[4 + j] = low ? (ushort)u : (ushort)(u >> 16);
  }
  return pb.v;
}

// ---- Phase D: attention. block=(qt,hp); 16 waves = 4 kg x 4 sp; full in-block reduce ----
__device__ __forceinline__ void phaseD(char* ws, void* out, SMem& sm,
                                       int isf32, int b, int t) {
  int qt = b >> 1, hp = b & 1;
  int v = t >> 6, kg = v & 3, sp = v >> 2;
  int vg = (2 * hp - kg + 8) & 3;
  int lane = t & 63, c = lane & 15, quad = lane >> 4;
  int n0 = qt * 16;
  const ushort* Qh = (const ushort*)(ws + OFF_QH);
  const ushort* Kh = (const ushort*)(ws + OFF_KH);
  const ushort* VsT = (const ushort*)(ws + OFF_VST);

  const ushort* q0row = Qh + ((hp    ) * N_PTS + n0 + c) * HD;
  const ushort* q1row = Qh + ((hp + 2) * N_PTS + n0 + c) * HD;
  bf16x8 qa00 = *(const bf16x8*)(q0row + quad * 8);
  bf16x8 qa01 = *(const bf16x8*)(q0row + 32 + quad * 8);
  bf16x8 qa10 = *(const bf16x8*)(q1row + quad * 8);
  bf16x8 qa11 = *(const bf16x8*)(q1row + 32 + quad * 8);

  f32x4 oacc0[4], oacc1[4];
#pragma unroll
  for (int i = 0; i < 4; ++i) {
    oacc0[i] = (f32x4){0.f, 0.f, 0.f, 0.f};
    oacc1[i] = (f32x4){0.f, 0.f, 0.f, 0.f};
  }
  float lp0 = 0.f, lp1 = 0.f;

  // 50 tiles of 32 keys split 13/13/12/12 across the 4 sp waves (R6 bug: was 25)
  int off = (sp == 0) ? 0 : (sp == 1) ? 13 : (sp == 2) ? 26 : 38;
  int iters = (sp < 2) ? 13 : 12;
  int kbase = off * 32;
  int sA = c + 16 * ((quad & 1) * 2);
  int sB = sA + 16;
  bool low = (quad < 2);
  const f32x4 z4 = (f32x4){0.f, 0.f, 0.f, 0.f};

  for (int it = 0; it < iters; ++it) {
    int key0 = kbase + it * 32;
    const ushort* krow = Kh + (kg * N_PTS + key0 + c) * HD;
    bf16x8 kb00 = *(const bf16x8*)(krow + quad * 8);
    bf16x8 kb01 = *(const bf16x8*)(krow + 32 + quad * 8);
    bf16x8 kb10 = *(const bf16x8*)(krow + 16 * HD + quad * 8);
    bf16x8 kb11 = *(const bf16x8*)(krow + 16 * HD + 32 + quad * 8);
    bf16x8 vb[4];
#pragma unroll
    for (int ds = 0; ds < 4; ++ds)
      vb[ds] = *(const bf16x8*)(VsT + (vg * HD + ds * 16 + c) * N_PTS + key0 + quad * 8);

    f32x4 s0 = __builtin_amdgcn_mfma_f32_16x16x32_bf16(kb00, qa00, z4, 0, 0, 0);
    s0 = __builtin_amdgcn_mfma_f32_16x16x32_bf16(kb01, qa01, s0, 0, 0, 0);
    f32x4 s1 = __builtin_amdgcn_mfma_f32_16x16x32_bf16(kb10, qa00, z4, 0, 0, 0);
    s1 = __builtin_amdgcn_mfma_f32_16x16x32_bf16(kb11, qa01, s1, 0, 0, 0);
    bf16x8 pb = build_pfrag(s0, s1, sA, sB, low, lp0);
#pragma unroll
    for (int ds = 0; ds < 4; ++ds)
      oacc0[ds] = __builtin_amdgcn_mfma_f32_16x16x32_bf16(vb[ds], pb, oacc0[ds], 0, 0, 0);

    s0 = __builtin_amdgcn_mfma_f32_16x16x32_bf16(kb00, qa10, z4, 0, 0, 0);
    s0 = __builtin_amdgcn_mfma_f32_16x16x32_bf16(kb01, qa11, s0, 0, 0, 0);
    s1 = __builtin_amdgcn_mfma_f32_16x16x32_bf16(kb10, qa10, z4, 0, 0, 0);
    s1 = __builtin_amdgcn_mfma_f32_16x16x32_bf16(kb11, qa11, s1, 0, 0, 0);
    bf16x8 pb1 = build_pfrag(s0, s1, sA, sB, low, lp1);
#pragma unroll
    for (int ds = 0; ds < 4; ++ds)
      oacc1[ds] = __builtin_amdgcn_mfma_f32_16x16x32_bf16(vb[ds], pb1, oacc1[ds], 0, 0, 0);
  }

  // per-wave L: sum the 4 quads (lanes c,c+16,c+32,c+48 hold partials for q=c)
  lp0 += __shfl_xor(lp0, 16, 64); lp0 += __shfl_xor(lp0, 32, 64);
  lp1 += __shfl_xor(lp1, 16, 64); lp1 += __shfl_xor(lp1, 32, 64);

#pragma unroll
  for (int h = 0; h < 2; ++h) {
    __syncthreads();
    f32x4* oa = h ? oacc1 : oacc0;
    int row = (kg * 4 + sp) * 16 + c;
#pragma unroll
    for (int ds = 0; ds < 4; ++ds) {
      union { __hip_bfloat162 hh; uint32_t u; } p01, p23;
      p01.hh = __float22bfloat162_rn(make_float2(oa[ds][0], oa[ds][1]));
      p23.hh = __float22bfloat162_rn(make_float2(oa[ds][2], oa[ds][3]));
      int d = ds * 16 + quad * 4;
      *(uint32_t*)&sm.u.d.obuf[row][d] = p01.u;
      *(uint32_t*)&sm.u.d.obuf[row][d + 2] = p23.u;
    }
    if (quad == 0) sm.u.d.lbuf[row] = h ? lp1 : lp0;
    __syncthreads();

    int q = t >> 6, d = t & 63;          // 16 x 64 = 1024 outputs
    int hq = hp + 2 * h;
    int wsel = h ? hp : ((hp + 2) & 3);  // kg carrying weight 2 for this head
    float acc = 0.f;
#pragma unroll
    for (int kg2 = 0; kg2 < 4; ++kg2) {
      float o = 0.f, l = 0.f;
#pragma unroll
      for (int sp2 = 0; sp2 < 4; ++sp2) {
        int r2 = (kg2 * 4 + sp2) * 16 + q;
        o += bf2f(sm.u.d.obuf[r2][d]);
        l += sm.u.d.lbuf[r2];
      }
      float w = (kg2 == wsel) ? 2.f : 1.f;
      acc += w * o / l;
    }
    int idx = (n0 + q) * 256 + hq * 64 + d;
    if (isf32) ((float*)out)[idx] = acc;
    else       ((ushort*)out)[idx] = f2bf(acc);
  }
}

// ================= cooperative megakernel =================
__global__ __launch_bounds__(1024, 4)
void k_mega(const void* __restrict__ x, const void* __restrict__ Wq,
            const void* __restrict__ bq, const void* __restrict__ Wk,
            const void* __restrict__ bk, const void* __restrict__ Wv,
            const void* __restrict__ bv, char* __restrict__ ws,
            void* __restrict__ out) {
  __shared__ SMem sm;
  cg::grid_group grid = cg::this_grid();
  int b = blockIdx.x, t = threadIdx.x;
  int isf32 = detect_f32((const ushort*)x, sm, t);
  phaseA(x, Wq, bq, Wk, bk, Wv, bv, ws, sm, isf32, b, t);
  grid.sync();
  phaseB(ws, b, t);
  grid.sync();
  phaseC(ws, b, t);
  grid.sync();
  phaseD(ws, out, sm, isf32, b, t);
}

// ================= non-cooperative fallback (same phase code) =================
__global__ __launch_bounds__(1024, 4)
void kA(const void* __restrict__ x, const void* __restrict__ Wq, const void* __restrict__ bq,
        const void* __restrict__ Wk, const void* __restrict__ bk, const void* __restrict__ Wv,
        const void* __restrict__ bv, char* __restrict__ ws) {
  __shared__ SMem sm;
  int isf32 = detect_f32((const ushort*)x, sm, threadIdx.x);
  phaseA(x, Wq, bq, Wk, bk, Wv, bv, ws, sm, isf32, blockIdx.x, threadIdx.x);
}
__global__ __launch_bounds__(1024, 4)
void kB(char* __restrict__ ws) { phaseB(ws, blockIdx.x, threadIdx.x); }
__global__ __launch_bounds__(1024, 4)
void kC(char* __restrict__ ws) { phaseC(ws, blockIdx.x, threadIdx.x); }
__global__ __launch_bounds__(1024, 4)
void kD(char* __restrict__ ws, void* __restrict__ out, const void* __restrict__ x) {
  __shared__ SMem sm;
  int isf32 = detect_f32((const ushort*)x, sm, threadIdx.x);
  phaseD(ws, out, sm, isf32, blockIdx.x, threadIdx.x);
}

extern "C" void kernel_launch(void* const* d_in, const int* in_sizes, int n_in,
                              void* d_out, int out_size, void* d_ws, size_t ws_size,
                              hipStream_t stream) {
  const void* x  = d_in[0];
  const void* Wq = d_in[1];
  const void* bq = d_in[2];
  const void* Wk = d_in[3];
  const void* bk = d_in[4];
  const void* Wv = d_in[5];
  const void* bv = d_in[6];
  char* ws = (char*)d_ws;
  void* out = d_out;
  void* args[9] = {&x, &Wq, &bq, &Wk, &bk, &Wv, &bv, &ws, &out};
  hipError_t err = hipLaunchCooperativeKernel((const void*)k_mega, dim3(200), dim3(1024),
                                              args, 0, stream);
  if (err != hipSuccess) {
    (void)hipGetLastError();  // clear sticky error; fall back to 4 plain launches
    kA<<<200, 1024, 0, stream>>>(x, Wq, bq, Wk, bk, Wv, bv, ws);
    kB<<<75, 1024, 0, stream>>>(ws);
    kC<<<200, 1024, 0, stream>>>(ws);
    kD<<<200, 1024, 0, stream>>>(ws, out, x);
  }
}

// Round 8
// 158.817 us; speedup vs baseline: 1.3806x; 1.3806x over previous
//
#include <hip/hip_runtime.h>
#include <hip/hip_bf16.h>
#include <stdint.h>

typedef __attribute__((ext_vector_type(8))) __bf16 bf16x8;
typedef __attribute__((ext_vector_type(4))) __bf16 bf16x4;
typedef __attribute__((ext_vector_type(4))) short short4v;
typedef __attribute__((ext_vector_type(4))) float f32x4;

#define N_PTS 1600
#define HD    64

// ---- ws layout (bytes), total 9.01 MB (<= 9.83 MB proven safe in R3/R4).
// [0, 6553600) is time-multiplexed: prep outputs Xc/WT/bias + VhT (all dead
// after k_smooth) -> Opart (written only by k_attn).
#define OFF_XC   0u          //  819200 : [1600][256] bf16 canonical x
#define OFF_WT   819200u     //  393216 : 3 x [256 o][256 k] bf16 transposed W
#define OFF_BIAS 1212416u    //    1536 : 3 x 256 bf16
#define OFF_VHT  1213952u    //  819200 : [4][64][1600] raw V^T
#define OFF_OP   0u          // 6553600 : [4 kg][1600 n][256 o] f32 weighted+normalized partials
#define OFF_QH   6553600u    //  819200 : [4][1600][64] bf16 Q (pre-scaled 1/16)
#define OFF_KH   7372800u    //  819200 : [4][1600][64] bf16 K
#define OFF_VST  8192000u    //  819200 : [4][64][1600] bf16 smoothed V^T

__device__ __forceinline__ float bf2f(ushort h) {
  union { uint32_t u; float f; } v; v.u = ((uint32_t)h) << 16; return v.f;
}
__device__ __forceinline__ ushort f2bf(float f) {
  union { float f; uint32_t u; } v; v.f = f;
  uint32_t u = v.u;
  return (ushort)((u + 0x7FFFu + ((u >> 16) & 1u)) >> 16);
}

// block-uniform dtype detect: sample x's first 4 KB; f32 buffers decode as huge/NaN bf16
__device__ __forceinline__ int detect_f32(const ushort* xu, int* shflag) {
  int t = threadIdx.x & 255;
  if (t == 0) *shflag = 0;
  __syncthreads();
  int local = 0;
#pragma unroll
  for (int i = 0; i < 4; ++i) {
    float v = bf2f(xu[(t * 4 + i) * 2]);
    if (!(fabsf(v) < 1e4f)) local = 1;
  }
  if (local) atomicOr(shflag, 1);
  __syncthreads();
  return *shflag;
}

// ---- prep: convert x/biases to bf16, transpose+convert the 3 weight matrices ----
__global__ void k_prep(const void* __restrict__ x, const void* __restrict__ Wq,
                       const void* __restrict__ bq, const void* __restrict__ Wk,
                       const void* __restrict__ bk, const void* __restrict__ Wv,
                       const void* __restrict__ bv, char* __restrict__ ws) {
  __shared__ int shflag;
  __shared__ ushort tileb[32][33];
  int isf32 = detect_f32((const ushort*)x, &shflag);
  int b = blockIdx.x, t = threadIdx.x;

  if (b < 400) {                       // x: 409600 elems, 1024/block
    ushort4 o;
    if (isf32) {
      float4 f = ((const float4*)x)[b * 256 + t];
      o.x = f2bf(f.x); o.y = f2bf(f.y); o.z = f2bf(f.z); o.w = f2bf(f.w);
    } else {
      o = ((const ushort4*)x)[b * 256 + t];
    }
    ((ushort4*)(ws + OFF_XC))[b * 256 + t] = o;
  } else if (b < 592) {                // W transpose: 64 32x32 tiles per z
    int w = b - 400, z = w >> 6, tile = w & 63;
    const void* W = (z == 0) ? Wq : ((z == 1) ? Wk : Wv);
    int o0 = (tile & 7) * 32, k0 = (tile >> 3) * 32;
    int tx = t & 31, ty = t >> 5;
#pragma unroll
    for (int i = 0; i < 32; i += 8) {
      int kk = (k0 + ty + i) * 256 + o0 + tx;
      tileb[ty + i][tx] = isf32 ? f2bf(((const float*)W)[kk]) : ((const ushort*)W)[kk];
    }
    __syncthreads();
    ushort* WT = (ushort*)(ws + OFF_WT) + z * 65536;
#pragma unroll
    for (int i = 0; i < 32; i += 8)
      WT[(o0 + ty + i) * 256 + k0 + tx] = tileb[tx][ty + i];
  } else {                             // biases
    ushort* bb = (ushort*)(ws + OFF_BIAS);
#pragma unroll
    for (int z = 0; z < 3; ++z) {
      const void* B = (z == 0) ? bq : ((z == 1) ? bk : bv);
      bb[z * 256 + t] = isf32 ? f2bf(((const float*)B)[t]) : ((const ushort*)B)[t];
    }
  }
}

// -------- projections: 4 waves/block = 4 heads. Q pre-scaled 1/16; V written transposed --------
__launch_bounds__(256)
__global__ void k_proj(const ushort* __restrict__ X, const ushort* __restrict__ WT,
                       const ushort* __restrict__ bias3,
                       ushort* __restrict__ Qh, ushort* __restrict__ Kh, ushort* __restrict__ VhT) {
  int z = blockIdx.z;
  const ushort* WTz = WT + z * 65536;
  const ushort* bias = bias3 + z * 256;
  int n0 = blockIdx.x * 16;
  int head = threadIdx.x >> 6;
  int lane = threadIdx.x & 63;
  int c = lane & 15, quad = lane >> 4;

  f32x4 acc[4];
#pragma unroll
  for (int i = 0; i < 4; ++i) acc[i] = (f32x4){0.f, 0.f, 0.f, 0.f};

  const ushort* xrow = X + (n0 + c) * 256;
#pragma unroll
  for (int kt = 0; kt < 8; ++kt) {
    bf16x8 a = *(const bf16x8*)(xrow + kt * 32 + quad * 8);
#pragma unroll
    for (int os = 0; os < 4; ++os) {
      bf16x8 bfr = *(const bf16x8*)(WTz + (head * 64 + os * 16 + c) * 256 + kt * 32 + quad * 8);
      acc[os] = __builtin_amdgcn_mfma_f32_16x16x32_bf16(a, bfr, acc[os], 0, 0, 0);
    }
  }
  if (z == 2) {
#pragma unroll
    for (int os = 0; os < 4; ++os) {
      float bval = bf2f(bias[head * 64 + os * 16 + c]);
      ushort4 v;
      v.x = f2bf(acc[os][0] + bval); v.y = f2bf(acc[os][1] + bval);
      v.z = f2bf(acc[os][2] + bval); v.w = f2bf(acc[os][3] + bval);
      *(ushort4*)(VhT + (head * 64 + os * 16 + c) * N_PTS + n0 + quad * 4) = v;
    }
  } else {
    float scale = (z == 0) ? 0.0625f : 1.0f;  // fold scores/sqrt(256) into Q
    ushort* out = (z == 0) ? Qh : Kh;
#pragma unroll
    for (int os = 0; os < 4; ++os) {
      float bval = bf2f(bias[head * 64 + os * 16 + c]);
#pragma unroll
      for (int r = 0; r < 4; ++r)
        out[head * (N_PTS * HD) + (n0 + quad * 4 + r) * HD + os * 16 + c] =
            f2bf((acc[os][r] + bval) * scale);
    }
  }
}

// --- smooth along m (coalesced): VsT[g][d][m] = sum_{sh in {-4,-2,0,2,4}} VhT[g][d][(m+sh)%1600]
__global__ void k_smooth(const ushort* __restrict__ VhT, ushort* __restrict__ VsT) {
  int idx = blockIdx.x * 256 + threadIdx.x;
  int m = idx % N_PTS;
  int base = idx - m;
  float s = 0.f;
#pragma unroll
  for (int sh = -4; sh <= 4; sh += 2)
    s += bf2f(VhT[base + ((m + sh + N_PTS) % N_PTS)]);
  VsT[idx] = f2bf(s);
}

// exp + pack 4 scores into the 16x16x16 A-fragment (keys quad*4+0..3 at q=c)
__device__ __forceinline__ short4v pack_p(const f32x4& s, float& lp) {
  float p0 = __expf(s[0]), p1 = __expf(s[1]), p2 = __expf(s[2]), p3 = __expf(s[3]);
  lp += (p0 + p1) + (p2 + p3);
  union { ushort us[4]; short4v v; } r;
  r.us[0] = f2bf(p0); r.us[1] = f2bf(p1); r.us[2] = f2bf(p2); r.us[3] = f2bf(p3);
  return r.v;
}

// ---- attention: block=(qt, hp*4+kg); 4 waves = 4 key-splits covering all 1600 keys.
// Sᵀ C-layout == PV A-fragment (16x16x16): NO shuffles, NO LDS in the K-loop.
// Full denominator in-block -> normalize+weight here; Opart[kg] summed by k_out. ----
__launch_bounds__(256, 4)
__global__ void k_attn(const ushort* __restrict__ Qh, const ushort* __restrict__ Kh,
                       const ushort* __restrict__ VsT, float* __restrict__ Opart) {
  int qt = blockIdx.x;
  int yy = blockIdx.y;           // hp*4 + kg
  int hp = yy >> 2, kg = yy & 3;
  int vg = (2 * hp - kg + 8) & 3;
  int tid = threadIdx.x, sp = tid >> 6, lane = tid & 63;
  int c = lane & 15, quad = lane >> 4;
  int n0 = qt * 16;

  __shared__ float obuf[4][16][68];   // [sp][q][d] f32 partials
  __shared__ float lbuf[4][16];

  const ushort* q0row = Qh + ((hp    ) * N_PTS + n0 + c) * HD;
  const ushort* q1row = Qh + ((hp + 2) * N_PTS + n0 + c) * HD;
  bf16x8 qa00 = *(const bf16x8*)(q0row + quad * 8);
  bf16x8 qa01 = *(const bf16x8*)(q0row + 32 + quad * 8);
  bf16x8 qa10 = *(const bf16x8*)(q1row + quad * 8);
  bf16x8 qa11 = *(const bf16x8*)(q1row + 32 + quad * 8);

  f32x4 oacc0[4], oacc1[4];
#pragma unroll
  for (int i = 0; i < 4; ++i) {
    oacc0[i] = (f32x4){0.f, 0.f, 0.f, 0.f};
    oacc1[i] = (f32x4){0.f, 0.f, 0.f, 0.f};
  }
  float lp0 = 0.f, lp1 = 0.f;

  // 50 tiles of 32 keys split 13/13/12/12 across the 4 sp waves
  int off = (sp == 0) ? 0 : (sp == 1) ? 13 : (sp == 2) ? 26 : 38;
  int iters = (sp < 2) ? 13 : 12;
  int kbase = off * 32;
  const f32x4 z4 = (f32x4){0.f, 0.f, 0.f, 0.f};

  // prologue: load first K tile (A-frags: K[key=c | c+16][dim])
  const ushort* krow = Kh + (kg * N_PTS + kbase + c) * HD;
  bf16x8 ka0 = *(const bf16x8*)(krow + quad * 8);
  bf16x8 ka1 = *(const bf16x8*)(krow + 32 + quad * 8);
  bf16x8 ka2 = *(const bf16x8*)(krow + 16 * HD + quad * 8);
  bf16x8 ka3 = *(const bf16x8*)(krow + 16 * HD + 32 + quad * 8);

  for (int it = 0; it < iters; ++it) {
    int key0 = kbase + it * 32;
    // current-iter V B-frags (b64: 4 keys contiguous at fixed d=ds*16+c)
    bf16x4 vb0[4], vb1[4];
#pragma unroll
    for (int ds = 0; ds < 4; ++ds) {
      const ushort* vp = VsT + (vg * HD + ds * 16 + c) * N_PTS + key0 + quad * 4;
      vb0[ds] = *(const bf16x4*)vp;
      vb1[ds] = *(const bf16x4*)(vp + 16);
    }
    // prefetch next-iter K (clamped; overlaps the compute below)
    int nk = kbase + ((it + 1 < iters) ? it + 1 : it) * 32;
    const ushort* krown = Kh + (kg * N_PTS + nk + c) * HD;
    bf16x8 kn0 = *(const bf16x8*)(krown + quad * 8);
    bf16x8 kn1 = *(const bf16x8*)(krown + 32 + quad * 8);
    bf16x8 kn2 = *(const bf16x8*)(krown + 16 * HD + quad * 8);
    bf16x8 kn3 = *(const bf16x8*)(krown + 16 * HD + 32 + quad * 8);

    f32x4 s;
    short4v pa;
    // subtile 0 (keys key0..key0+15): head 0 then head 1 (shared K/V frags)
    s = __builtin_amdgcn_mfma_f32_16x16x32_bf16(ka0, qa00, z4, 0, 0, 0);
    s = __builtin_amdgcn_mfma_f32_16x16x32_bf16(ka1, qa01, s, 0, 0, 0);
    pa = pack_p(s, lp0);
#pragma unroll
    for (int ds = 0; ds < 4; ++ds)
      oacc0[ds] = __builtin_amdgcn_mfma_f32_16x16x16bf16_1k(pa, vb0[ds], oacc0[ds], 0, 0, 0);

    s = __builtin_amdgcn_mfma_f32_16x16x32_bf16(ka0, qa10, z4, 0, 0, 0);
    s = __builtin_amdgcn_mfma_f32_16x16x32_bf16(ka1, qa11, s, 0, 0, 0);
    pa = pack_p(s, lp1);
#pragma unroll
    for (int ds = 0; ds < 4; ++ds)
      oacc1[ds] = __builtin_amdgcn_mfma_f32_16x16x16bf16_1k(pa, vb0[ds], oacc1[ds], 0, 0, 0);

    // subtile 1 (keys key0+16..key0+31)
    s = __builtin_amdgcn_mfma_f32_16x16x32_bf16(ka2, qa00, z4, 0, 0, 0);
    s = __builtin_amdgcn_mfma_f32_16x16x32_bf16(ka3, qa01, s, 0, 0, 0);
    pa = pack_p(s, lp0);
#pragma unroll
    for (int ds = 0; ds < 4; ++ds)
      oacc0[ds] = __builtin_amdgcn_mfma_f32_16x16x16bf16_1k(pa, vb1[ds], oacc0[ds], 0, 0, 0);

    s = __builtin_amdgcn_mfma_f32_16x16x32_bf16(ka2, qa10, z4, 0, 0, 0);
    s = __builtin_amdgcn_mfma_f32_16x16x32_bf16(ka3, qa11, s, 0, 0, 0);
    pa = pack_p(s, lp1);
#pragma unroll
    for (int ds = 0; ds < 4; ++ds)
      oacc1[ds] = __builtin_amdgcn_mfma_f32_16x16x16bf16_1k(pa, vb1[ds], oacc1[ds], 0, 0, 0);

    ka0 = kn0; ka1 = kn1; ka2 = kn2; ka3 = kn3;
  }

  // full denominator per q=c: sum the 4 quads' partials
  lp0 += __shfl_xor(lp0, 16, 64); lp0 += __shfl_xor(lp0, 32, 64);
  lp1 += __shfl_xor(lp1, 16, 64); lp1 += __shfl_xor(lp1, 32, 64);

  // O is in natural C-layout: oaccX[ds] reg r = O[q=quad*4+r][d=ds*16+c]
#pragma unroll
  for (int h = 0; h < 2; ++h) {
    __syncthreads();
    const f32x4* oa = h ? oacc1 : oacc0;
#pragma unroll
    for (int ds = 0; ds < 4; ++ds)
#pragma unroll
      for (int r = 0; r < 4; ++r)
        obuf[sp][quad * 4 + r][ds * 16 + c] = oa[ds][r];
    if (quad == 0) lbuf[sp][c] = h ? lp1 : lp0;
    __syncthreads();

    int q = tid >> 4, d0 = (tid & 15) * 4;
    f32x4 a = *(const f32x4*)&obuf[0][q][d0];
    a += *(const f32x4*)&obuf[1][q][d0];
    a += *(const f32x4*)&obuf[2][q][d0];
    a += *(const f32x4*)&obuf[3][q][d0];
    float l = lbuf[0][q] + lbuf[1][q] + lbuf[2][q] + lbuf[3][q];
    int hq = hp + 2 * h;
    int wsel = h ? hp : ((hp + 2) & 3);  // kg carrying weight 2 for this head
    float w = (kg == wsel) ? 2.f : 1.f;
    f32x4 o = a * (w / l);
    *(f32x4*)&Opart[(size_t)kg * 409600 + (size_t)(n0 + q) * 256 + hq * 64 + d0] = o;
  }
}

// ---- final: out = sum of the 4 kg slices (already weighted+normalized), cast ----
__global__ void k_out(const float* __restrict__ Opart, const void* __restrict__ x,
                      void* __restrict__ out) {
  __shared__ int shflag;
  int isf32 = detect_f32((const ushort*)x, &shflag);
  int idx = blockIdx.x * 256 + threadIdx.x;
  float s = Opart[idx] + Opart[409600 + idx] + Opart[819200 + idx] + Opart[1228800 + idx];
  if (isf32) ((float*)out)[idx] = s;
  else       ((ushort*)out)[idx] = f2bf(s);
}

extern "C" void kernel_launch(void* const* d_in, const int* in_sizes, int n_in,
                              void* d_out, int out_size, void* d_ws, size_t ws_size,
                              hipStream_t stream) {
  char* ws = (char*)d_ws;
  ushort* Xc    = (ushort*)(ws + OFF_XC);
  ushort* WT    = (ushort*)(ws + OFF_WT);
  ushort* bias3 = (ushort*)(ws + OFF_BIAS);
  ushort* VhT   = (ushort*)(ws + OFF_VHT);
  float*  Opart = (float*)(ws + OFF_OP);
  ushort* Qh    = (ushort*)(ws + OFF_QH);
  ushort* Kh    = (ushort*)(ws + OFF_KH);
  ushort* VsT   = (ushort*)(ws + OFF_VST);

  k_prep<<<593, 256, 0, stream>>>(d_in[0], d_in[1], d_in[2], d_in[3],
                                  d_in[4], d_in[5], d_in[6], ws);
  k_proj<<<dim3(100, 1, 3), 256, 0, stream>>>(Xc, WT, bias3, Qh, Kh, VhT);
  k_smooth<<<1600, 256, 0, stream>>>(VhT, VsT);
  k_attn<<<dim3(100, 8), 256, 0, stream>>>(Qh, Kh, VsT, Opart);
  k_out<<<1600, 256, 0, stream>>>(Opart, d_in[0], d_out);
}

// Round 9
// 134.780 us; speedup vs baseline: 1.6268x; 1.1783x over previous
//
#include <hip/hip_runtime.h>
#include <hip/hip_bf16.h>
#include <stdint.h>

typedef __attribute__((ext_vector_type(8))) __bf16 bf16x8;
typedef __attribute__((ext_vector_type(4))) float f32x4;

#define N_PTS 1600
#define HD    64

// ---- ws layout (bytes), total 9.22 MB (9.83 MB proven safe R3/R4).
// [0, 6553600) time-multiplexed: Xc/WT/bias/VhT (dead after k_smooth) -> Opart.
#define OFF_XC   0u          //  819200 : [1600][256] bf16 canonical x
#define OFF_WT   819200u     //  393216 : 3 x [256 o][256 k] bf16 transposed W
#define OFF_BIAS 1212416u    //    1536 : 3 x 256 bf16
#define OFF_VHT  1213952u    //  819200 : [4][64][1600] raw V^T
#define OFF_OP   0u          // 6553600 : [2 z][4 kg][1600 n][256 o] bf16 O partials
#define OFF_LP   6553600u    //  204800 : [2 z][4 kg][4 hq][1600 n] f32 L partials
#define OFF_QH   6758400u    //  819200 : [4][1600][64] bf16 Q (pre-scaled by log2e/16)
#define OFF_KH   7577600u    //  819200 : [4][1600][64] bf16 K
#define OFF_VST  8396800u    //  819200 : [4][64][1600] bf16 smoothed V^T

__device__ __forceinline__ float bf2f(ushort h) {
  union { uint32_t u; float f; } v; v.u = ((uint32_t)h) << 16; return v.f;
}
__device__ __forceinline__ ushort f2bf(float f) {
  union { float f; uint32_t u; } v; v.f = f;
  uint32_t u = v.u;
  return (ushort)((u + 0x7FFFu + ((u >> 16) & 1u)) >> 16);
}
__device__ __forceinline__ uint32_t pk2(float a, float b) {
  union { __hip_bfloat162 h; uint32_t u; } cv;
  cv.h = __float22bfloat162_rn(make_float2(a, b));
  return cv.u;
}

// block-uniform dtype detect: sample x's first 4 KB; f32 buffers decode as huge/NaN bf16
__device__ __forceinline__ int detect_f32(const ushort* xu, int* shflag) {
  int t = threadIdx.x & 255;
  if (t == 0) *shflag = 0;
  __syncthreads();
  int local = 0;
#pragma unroll
  for (int i = 0; i < 4; ++i) {
    float v = bf2f(xu[(t * 4 + i) * 2]);
    if (!(fabsf(v) < 1e4f)) local = 1;
  }
  if (local) atomicOr(shflag, 1);
  __syncthreads();
  return *shflag;
}

// ---- prep: convert x/biases to bf16, transpose+convert the 3 weight matrices ----
__global__ void k_prep(const void* __restrict__ x, const void* __restrict__ Wq,
                       const void* __restrict__ bq, const void* __restrict__ Wk,
                       const void* __restrict__ bk, const void* __restrict__ Wv,
                       const void* __restrict__ bv, char* __restrict__ ws) {
  __shared__ int shflag;
  __shared__ ushort tileb[32][33];
  int isf32 = detect_f32((const ushort*)x, &shflag);
  int b = blockIdx.x, t = threadIdx.x;

  if (b < 400) {                       // x: 409600 elems, 1024/block
    ushort4 o;
    if (isf32) {
      float4 f = ((const float4*)x)[b * 256 + t];
      o.x = f2bf(f.x); o.y = f2bf(f.y); o.z = f2bf(f.z); o.w = f2bf(f.w);
    } else {
      o = ((const ushort4*)x)[b * 256 + t];
    }
    ((ushort4*)(ws + OFF_XC))[b * 256 + t] = o;
  } else if (b < 592) {                // W transpose: 64 32x32 tiles per z
    int w = b - 400, z = w >> 6, tile = w & 63;
    const void* W = (z == 0) ? Wq : ((z == 1) ? Wk : Wv);
    int o0 = (tile & 7) * 32, k0 = (tile >> 3) * 32;
    int tx = t & 31, ty = t >> 5;
#pragma unroll
    for (int i = 0; i < 32; i += 8) {
      int kk = (k0 + ty + i) * 256 + o0 + tx;
      tileb[ty + i][tx] = isf32 ? f2bf(((const float*)W)[kk]) : ((const ushort*)W)[kk];
    }
    __syncthreads();
    ushort* WT = (ushort*)(ws + OFF_WT) + z * 65536;
#pragma unroll
    for (int i = 0; i < 32; i += 8)
      WT[(o0 + ty + i) * 256 + k0 + tx] = tileb[tx][ty + i];
  } else {                             // biases
    ushort* bb = (ushort*)(ws + OFF_BIAS);
#pragma unroll
    for (int z = 0; z < 3; ++z) {
      const void* B = (z == 0) ? bq : ((z == 1) ? bk : bv);
      bb[z * 256 + t] = isf32 ? f2bf(((const float*)B)[t]) : ((const ushort*)B)[t];
    }
  }
}

// -------- projections: 4 waves/block = 4 heads. Q pre-scaled log2e/16; V transposed --------
__launch_bounds__(256)
__global__ void k_proj(const ushort* __restrict__ X, const ushort* __restrict__ WT,
                       const ushort* __restrict__ bias3,
                       ushort* __restrict__ Qh, ushort* __restrict__ Kh, ushort* __restrict__ VhT) {
  int z = blockIdx.z;
  const ushort* WTz = WT + z * 65536;
  const ushort* bias = bias3 + z * 256;
  int n0 = blockIdx.x * 16;
  int head = threadIdx.x >> 6;
  int lane = threadIdx.x & 63;
  int c = lane & 15, quad = lane >> 4;

  f32x4 acc[4];
#pragma unroll
  for (int i = 0; i < 4; ++i) acc[i] = (f32x4){0.f, 0.f, 0.f, 0.f};

  const ushort* xrow = X + (n0 + c) * 256;
#pragma unroll
  for (int kt = 0; kt < 8; ++kt) {
    bf16x8 a = *(const bf16x8*)(xrow + kt * 32 + quad * 8);
#pragma unroll
    for (int os = 0; os < 4; ++os) {
      bf16x8 bfr = *(const bf16x8*)(WTz + (head * 64 + os * 16 + c) * 256 + kt * 32 + quad * 8);
      acc[os] = __builtin_amdgcn_mfma_f32_16x16x32_bf16(a, bfr, acc[os], 0, 0, 0);
    }
  }
  if (z == 2) {
#pragma unroll
    for (int os = 0; os < 4; ++os) {
      float bval = bf2f(bias[head * 64 + os * 16 + c]);
      ushort4 v;
      v.x = f2bf(acc[os][0] + bval); v.y = f2bf(acc[os][1] + bval);
      v.z = f2bf(acc[os][2] + bval); v.w = f2bf(acc[os][3] + bval);
      *(ushort4*)(VhT + (head * 64 + os * 16 + c) * N_PTS + n0 + quad * 4) = v;
    }
  } else {
    // fold 1/sqrt(256) AND log2(e) into Q so the softmax uses exp2
    float scale = (z == 0) ? 0.0625f * 1.44269504088896f : 1.0f;
    ushort* out = (z == 0) ? Qh : Kh;
#pragma unroll
    for (int os = 0; os < 4; ++os) {
      float bval = bf2f(bias[head * 64 + os * 16 + c]);
#pragma unroll
      for (int r = 0; r < 4; ++r)
        out[head * (N_PTS * HD) + (n0 + quad * 4 + r) * HD + os * 16 + c] =
            f2bf((acc[os][r] + bval) * scale);
    }
  }
}

// --- smooth along m (coalesced): VsT[g][d][m] = sum_{sh in {-4,-2,0,2,4}} VhT[g][d][(m+sh)%1600]
__global__ void k_smooth(const ushort* __restrict__ VhT, ushort* __restrict__ VsT) {
  int idx = blockIdx.x * 256 + threadIdx.x;
  int m = idx % N_PTS;
  int base = idx - m;
  float s = 0.f;
#pragma unroll
  for (int sh = -4; sh <= 4; sh += 2)
    s += bf2f(VhT[base + ((m + sh + N_PTS) % N_PTS)]);
  VsT[idx] = f2bf(s);
}

// exp2 + pack 8 scores into the 16x16x32 PV A-fragment.
// s0 regs r = keys quad*8+r, s1 regs r = keys quad*8+4+r (via permuted K load)
// -> pa holds P[q=c][key=quad*8+j], j=0..7 == A[m=c][k=quad*8+j]. No shuffles.
__device__ __forceinline__ bf16x8 pack_p8(const f32x4& s0, const f32x4& s1, float& lp) {
  float e0 = exp2f(s0[0]), e1 = exp2f(s0[1]), e2 = exp2f(s0[2]), e3 = exp2f(s0[3]);
  float e4 = exp2f(s1[0]), e5 = exp2f(s1[1]), e6 = exp2f(s1[2]), e7 = exp2f(s1[3]);
  lp += ((e0 + e1) + (e2 + e3)) + ((e4 + e5) + (e6 + e7));
  union { uint32_t u[4]; bf16x8 v; } r;
  r.u[0] = pk2(e0, e1); r.u[1] = pk2(e2, e3);
  r.u[2] = pk2(e4, e5); r.u[3] = pk2(e6, e7);
  return r.v;
}

// ---- attention: grid (100 qt, 8 = hp*4+kg, 2 z). 4 waves = 4 key-subsplits.
// Permuted-key QK makes S^T directly PV-A-layout; all loads b128; LDS only in epilogue.
__launch_bounds__(256, 4)
__global__ void k_attn(const ushort* __restrict__ Qh, const ushort* __restrict__ Kh,
                       const ushort* __restrict__ VsT, ushort* __restrict__ Opart,
                       float* __restrict__ Lpart) {
  int qt = blockIdx.x;
  int yy = blockIdx.y;           // hp*4 + kg
  int z  = blockIdx.z;           // key half
  int hp = yy >> 2, kg = yy & 3;
  int vg = (2 * hp - kg + 8) & 3;
  int tid = threadIdx.x, sp = tid >> 6, lane = tid & 63;
  int c = lane & 15, quad = lane >> 4;
  int n0 = qt * 16;
  int perm = ((c >> 2) << 3) + (c & 3);   // key permutation for QK A-frag

  __shared__ float obuf[4][16][68];   // [sp][q][d] f32 partials (epilogue only)
  __shared__ float lbuf[4][16];

  const ushort* q0row = Qh + ((hp    ) * N_PTS + n0 + c) * HD;
  const ushort* q1row = Qh + ((hp + 2) * N_PTS + n0 + c) * HD;
  bf16x8 qa00 = *(const bf16x8*)(q0row + quad * 8);
  bf16x8 qa01 = *(const bf16x8*)(q0row + 32 + quad * 8);
  bf16x8 qa10 = *(const bf16x8*)(q1row + quad * 8);
  bf16x8 qa11 = *(const bf16x8*)(q1row + 32 + quad * 8);

  f32x4 oacc0[4], oacc1[4];
#pragma unroll
  for (int i = 0; i < 4; ++i) {
    oacc0[i] = (f32x4){0.f, 0.f, 0.f, 0.f};
    oacc1[i] = (f32x4){0.f, 0.f, 0.f, 0.f};
  }
  float lp0 = 0.f, lp1 = 0.f;

  // 25 tiles per z-half, split 7/6/6/6 across the 4 sp waves
  int off = (sp == 0) ? 0 : (sp == 1) ? 7 : (sp == 2) ? 13 : 19;
  int iters = (sp == 0) ? 7 : 6;
  int kbase = z * 800 + off * 32;
  const f32x4 z4 = (f32x4){0.f, 0.f, 0.f, 0.f};

  for (int it = 0; it < iters; ++it) {
    int key0 = kbase + it * 32;
    const ushort* kr = Kh + (kg * N_PTS + key0 + perm) * HD;
    bf16x8 ka0 = *(const bf16x8*)(kr + quad * 8);            // keys quad*8+r, dims 0..31
    bf16x8 ka1 = *(const bf16x8*)(kr + 32 + quad * 8);       // dims 32..63
    bf16x8 kb0 = *(const bf16x8*)(kr + 4 * HD + quad * 8);   // keys quad*8+4+r
    bf16x8 kb1 = *(const bf16x8*)(kr + 4 * HD + 32 + quad * 8);
    bf16x8 vb[4];
#pragma unroll
    for (int ds = 0; ds < 4; ++ds)
      vb[ds] = *(const bf16x8*)(VsT + (vg * HD + ds * 16 + c) * N_PTS + key0 + quad * 8);

    // head 0
    f32x4 s0 = __builtin_amdgcn_mfma_f32_16x16x32_bf16(ka0, qa00, z4, 0, 0, 0);
    s0 = __builtin_amdgcn_mfma_f32_16x16x32_bf16(ka1, qa01, s0, 0, 0, 0);
    f32x4 s1 = __builtin_amdgcn_mfma_f32_16x16x32_bf16(kb0, qa00, z4, 0, 0, 0);
    s1 = __builtin_amdgcn_mfma_f32_16x16x32_bf16(kb1, qa01, s1, 0, 0, 0);
    bf16x8 pa = pack_p8(s0, s1, lp0);
#pragma unroll
    for (int ds = 0; ds < 4; ++ds)
      oacc0[ds] = __builtin_amdgcn_mfma_f32_16x16x32_bf16(pa, vb[ds], oacc0[ds], 0, 0, 0);

    // head 1 (hp+2): same K and V fragments
    s0 = __builtin_amdgcn_mfma_f32_16x16x32_bf16(ka0, qa10, z4, 0, 0, 0);
    s0 = __builtin_amdgcn_mfma_f32_16x16x32_bf16(ka1, qa11, s0, 0, 0, 0);
    s1 = __builtin_amdgcn_mfma_f32_16x16x32_bf16(kb0, qa10, z4, 0, 0, 0);
    s1 = __builtin_amdgcn_mfma_f32_16x16x32_bf16(kb1, qa11, s1, 0, 0, 0);
    bf16x8 pa1 = pack_p8(s0, s1, lp1);
#pragma unroll
    for (int ds = 0; ds < 4; ++ds)
      oacc1[ds] = __builtin_amdgcn_mfma_f32_16x16x32_bf16(pa1, vb[ds], oacc1[ds], 0, 0, 0);
  }

  // per-wave L: lanes c, c+16, c+32, c+48 hold disjoint-key partials for q=c
  lp0 += __shfl_xor(lp0, 16, 64); lp0 += __shfl_xor(lp0, 32, 64);
  lp1 += __shfl_xor(lp1, 16, 64); lp1 += __shfl_xor(lp1, 32, 64);

  // O C-layout: oaccX[ds] reg r = O[q=quad*4+r][d=ds*16+c]; reduce sp in LDS
#pragma unroll
  for (int h = 0; h < 2; ++h) {
    __syncthreads();
    const f32x4* oa = h ? oacc1 : oacc0;
#pragma unroll
    for (int ds = 0; ds < 4; ++ds)
#pragma unroll
      for (int r = 0; r < 4; ++r)
        obuf[sp][quad * 4 + r][ds * 16 + c] = oa[ds][r];
    if (quad == 0) lbuf[sp][c] = h ? lp1 : lp0;
    __syncthreads();

    int q = tid >> 4, d0 = (tid & 15) * 4;
    f32x4 a = *(const f32x4*)&obuf[0][q][d0];
    a += *(const f32x4*)&obuf[1][q][d0];
    a += *(const f32x4*)&obuf[2][q][d0];
    a += *(const f32x4*)&obuf[3][q][d0];
    float l = lbuf[0][q] + lbuf[1][q] + lbuf[2][q] + lbuf[3][q];
    int hq = hp + 2 * h;
    union { uint32_t u[2]; } wv;
    wv.u[0] = pk2(a[0], a[1]);
    wv.u[1] = pk2(a[2], a[3]);
    *(uint2*)&Opart[(size_t)((z * 4 + kg) * N_PTS + n0 + q) * 256 + hq * 64 + d0] =
        *(uint2*)wv.u;
    if ((tid & 15) == 0)
      Lpart[((z * 4 + kg) * 4 + hq) * N_PTS + n0 + q] = l;
  }
}

// ---- final: out = sum_kg w(kg,hq) * (sum_z O) / (sum_z L), cast per detected dtype ----
__global__ void k_out(const ushort* __restrict__ Opart, const float* __restrict__ Lpart,
                      const void* __restrict__ x, void* __restrict__ out) {
  __shared__ int shflag;
  int isf32 = detect_f32((const ushort*)x, &shflag);
  int idx = blockIdx.x * 256 + threadIdx.x;
  int n = idx >> 8, o = idx & 255, hq = o >> 6;
  float acc = 0.f;
#pragma unroll
  for (int kg = 0; kg < 4; ++kg) {
    float num = bf2f(Opart[(size_t)((0 + kg) * N_PTS + n) * 256 + o]) +
                bf2f(Opart[(size_t)((4 + kg) * N_PTS + n) * 256 + o]);
    float l = Lpart[((0 + kg) * 4 + hq) * N_PTS + n] +
              Lpart[((4 + kg) * 4 + hq) * N_PTS + n];
    float w = (kg == ((hq + 2) & 3)) ? 2.f : 1.f;
    acc += w * num / l;
  }
  if (isf32) ((float*)out)[idx] = acc;
  else       ((ushort*)out)[idx] = f2bf(acc);
}

extern "C" void kernel_launch(void* const* d_in, const int* in_sizes, int n_in,
                              void* d_out, int out_size, void* d_ws, size_t ws_size,
                              hipStream_t stream) {
  char* ws = (char*)d_ws;
  ushort* Xc    = (ushort*)(ws + OFF_XC);
  ushort* WT    = (ushort*)(ws + OFF_WT);
  ushort* bias3 = (ushort*)(ws + OFF_BIAS);
  ushort* VhT   = (ushort*)(ws + OFF_VHT);
  ushort* Opart = (ushort*)(ws + OFF_OP);
  float*  Lpart = (float*)(ws + OFF_LP);
  ushort* Qh    = (ushort*)(ws + OFF_QH);
  ushort* Kh    = (ushort*)(ws + OFF_KH);
  ushort* VsT   = (ushort*)(ws + OFF_VST);

  k_prep<<<593, 256, 0, stream>>>(d_in[0], d_in[1], d_in[2], d_in[3],
                                  d_in[4], d_in[5], d_in[6], ws);
  k_proj<<<dim3(100, 1, 3), 256, 0, stream>>>(Xc, WT, bias3, Qh, Kh, VhT);
  k_smooth<<<1600, 256, 0, stream>>>(VhT, VsT);
  k_attn<<<dim3(100, 8, 2), 256, 0, stream>>>(Qh, Kh, VsT, Opart, Lpart);
  k_out<<<1600, 256, 0, stream>>>(Opart, Lpart, d_in[0], d_out);
}